// Round 1
// baseline (1125.988 us; speedup 1.0000x reference)
//
#include <hip/hip_runtime.h>
#include <hip/hip_bf16.h>

// Kalman recurrence, exact chunked parallelization (all fp32, round 1).
//   x[k+1] = M x[k] + L y[:,k],  M = A - L H,  yhat[:,k] = H x[k], x[0]=0
// Chunk T=16:  yhat[cT+t] = F_t x_c + sum_{s<t} K_{t-1-s} y[cT+s]
//   F_t = H M^t (32x64), K_d = H M^d L (32x32), v_c = sum_t M^{T-1-t} L y[cT+t]
//   x_{c+1} = P x_c + v_c, P = M^16.  3-level scan over C=16384 chunks.

#define NSTEP 262144
#define T 16
#define CCH (NSTEP / T)          // 16384 chunks
#define KDIM (64 + 32 * T)       // 576
#define MOUT (32 * T)            // 512
#define NBLK 128                 // scan blocks
#define SB (CCH / NBLK)          // 128 chunks per scan block

// ---- workspace layout (floats) ----
#define OFF_Z  0                         // Z: [576][CCH]  rows 0..63 = x_c, 64.. = packed y
#define SZ_Z   (KDIM * CCH)
#define OFF_VT (OFF_Z + SZ_Z)            // VT: [CCH][64]  chunk summaries v_c (transposed)
#define SZ_VT  (CCH * 64)
#define OFF_MP (OFF_VT + SZ_VT)          // M powers: slots {M,M2,M4,M8,M16=P,M2048=Q} x4096
#define SZ_MP  (6 * 4096)
#define OFF_F  (OFF_MP + SZ_MP)          // F_t: 16 x (32x64)
#define SZ_F   (16 * 2048)
#define OFF_G  (OFF_F + SZ_F)            // G_t = M^t L: 16 x (64x32)
#define SZ_G   (16 * 2048)
#define OFF_KD (OFF_G + SZ_G)            // K_d: 15 x (32x32)
#define SZ_KD  (15 * 1024)
#define OFF_BO (OFF_KD + SZ_KD)          // BigOut: [512][576], rows permuted r' = i*16 + t
#define SZ_BO  (MOUT * KDIM)
#define OFF_GC (OFF_BO + SZ_BO)          // Gcat: [64][512]
#define SZ_GC  (64 * 512)
#define OFF_W  (OFF_GC + SZ_GC)          // per-scan-block summaries w_b: [128][64]
#define SZ_W   (NBLK * 64)
#define OFF_XB (OFF_W + SZ_W)            // block start states X_b: [128][64]

// ---------------- pack: Z[64 + t*32 + i][c] = y[i][c*16+t] ----------------
__global__ __launch_bounds__(256) void k_pack(const float* __restrict__ y,
                                              float* __restrict__ Z) {
  int g = blockIdx.x * 256 + threadIdx.x;      // over 32 * 65536 float4s
  int i = g >> 16;
  int k0 = (g & 65535) << 2;
  int c = k0 >> 4;
  int t0 = k0 & 15;
  const float4 v = *reinterpret_cast<const float4*>(y + (size_t)i * NSTEP + k0);
  size_t base = (size_t)(64 + t0 * 32 + i) * CCH + c;
  Z[base] = v.x;
  Z[base + (size_t)32 * CCH] = v.y;
  Z[base + (size_t)64 * CCH] = v.z;
  Z[base + (size_t)96 * CCH] = v.w;
}

// ------------- P1: M = A - L H, then squaring chain in LDS -------------
__global__ __launch_bounds__(1024) void k_p1(const float* __restrict__ A,
                                             const float* __restrict__ H,
                                             const float* __restrict__ L,
                                             float* __restrict__ MP) {
  __shared__ float sm[2][64 * 68];
  const int tid = threadIdx.x;
  const int i = tid >> 4;
  const int j0 = (tid & 15) << 2;
  float a0 = A[i * 64 + j0 + 0], a1 = A[i * 64 + j0 + 1];
  float a2 = A[i * 64 + j0 + 2], a3 = A[i * 64 + j0 + 3];
  for (int q = 0; q < 32; ++q) {
    const float l = L[i * 32 + q];
    a0 -= l * H[q * 64 + j0 + 0];
    a1 -= l * H[q * 64 + j0 + 1];
    a2 -= l * H[q * 64 + j0 + 2];
    a3 -= l * H[q * 64 + j0 + 3];
  }
  sm[0][i * 68 + j0 + 0] = a0; sm[0][i * 68 + j0 + 1] = a1;
  sm[0][i * 68 + j0 + 2] = a2; sm[0][i * 68 + j0 + 3] = a3;
  MP[i * 64 + j0 + 0] = a0; MP[i * 64 + j0 + 1] = a1;
  MP[i * 64 + j0 + 2] = a2; MP[i * 64 + j0 + 3] = a3;
  __syncthreads();
  int cur = 0;
  for (int s = 1; s <= 11; ++s) {   // powers 2,4,8,16,...,2048
    float c0 = 0.f, c1 = 0.f, c2 = 0.f, c3 = 0.f;
    for (int k = 0; k < 64; ++k) {
      const float r = sm[cur][i * 68 + k];
      const float* col = &sm[cur][k * 68 + j0];
      c0 += r * col[0]; c1 += r * col[1]; c2 += r * col[2]; c3 += r * col[3];
    }
    sm[cur ^ 1][i * 68 + j0 + 0] = c0; sm[cur ^ 1][i * 68 + j0 + 1] = c1;
    sm[cur ^ 1][i * 68 + j0 + 2] = c2; sm[cur ^ 1][i * 68 + j0 + 3] = c3;
    const int slot = (s <= 4) ? s : (s == 11 ? 5 : -1);
    if (slot >= 0) {
      MP[slot * 4096 + i * 64 + j0 + 0] = c0;
      MP[slot * 4096 + i * 64 + j0 + 1] = c1;
      MP[slot * 4096 + i * 64 + j0 + 2] = c2;
      MP[slot * 4096 + i * 64 + j0 + 3] = c3;
    }
    cur ^= 1;
    __syncthreads();
  }
}

// ------ P2: F/G doubling, K_d, assemble BigOut (permuted rows) + Gcat ------
__global__ __launch_bounds__(1024) void k_p2(const float* __restrict__ H,
                                             const float* __restrict__ L,
                                             const float* __restrict__ MP,
                                             float* __restrict__ ws) {
  float* Fb = ws + OFF_F;
  float* Gb = ws + OFF_G;
  float* Kd = ws + OFF_KD;
  float* BO = ws + OFF_BO;
  float* GC = ws + OFF_GC;
  volatile const float* Fv = Fb;   // volatile: intra-kernel global RAW, bypass L1
  volatile const float* Gv = Gb;
  volatile const float* Kv = Kd;
  const int tid = threadIdx.x;
  for (int e = tid; e < 2048; e += 1024) Fb[e] = H[e];   // F_0 = H
  for (int e = tid; e < 2048; e += 1024) Gb[e] = L[e];   // G_0 = L
  __threadfence(); __syncthreads();
  for (int r = 0; r < 4; ++r) {                // doubling rounds
    const int nf = 1 << r;
    const float* Mp = MP + r * 4096;           // M^{2^r}
    for (int e = tid; e < nf * 2048; e += 1024) {
      const int t = e >> 11, i = (e >> 6) & 31, j = e & 63;
      float acc = 0.f;
      for (int q = 0; q < 64; ++q) acc += Fv[t * 2048 + i * 64 + q] * Mp[q * 64 + j];
      Fb[(nf + t) * 2048 + i * 64 + j] = acc;  // F_{t+nf} = F_t M^{nf}
    }
    for (int e = tid; e < nf * 2048; e += 1024) {
      const int t = e >> 11, i = (e >> 5) & 63, q = e & 31;
      float acc = 0.f;
      for (int p = 0; p < 64; ++p) acc += Mp[i * 64 + p] * Gv[t * 2048 + p * 32 + q];
      Gb[(nf + t) * 2048 + i * 32 + q] = acc;  // G_{t+nf} = M^{nf} G_t
    }
    __threadfence(); __syncthreads();
  }
  for (int e = tid; e < 15 * 1024; e += 1024) { // K_d = F_d L
    const int d = e >> 10, i = (e >> 5) & 31, q = e & 31;
    float acc = 0.f;
    for (int j = 0; j < 64; ++j) acc += Fv[d * 2048 + i * 64 + j] * L[j * 32 + q];
    Kd[d * 1024 + i * 32 + q] = acc;
  }
  __threadfence(); __syncthreads();
  for (int e = tid; e < MOUT * KDIM; e += 1024) {  // BigOut, rows r' = i*16+t
    const int rr = e / KDIM;
    const int f = e - rr * KDIM;
    const int i = rr >> 4;
    const int t = rr & 15;
    float v;
    if (f < 64) v = Fv[t * 2048 + i * 64 + f];
    else {
      const int s = (f - 64) >> 5;
      const int q = (f - 64) & 31;
      v = (s < t) ? Kv[(t - 1 - s) * 1024 + i * 32 + q] : 0.f;
    }
    BO[e] = v;
  }
  for (int e = tid; e < 64 * 512; e += 1024) {     // Gcat[j][t*32+i] = G_{15-t}[j][i]
    const int j = e >> 9, f = e & 511, t = f >> 5, ii = f & 31;
    GC[e] = Gv[(15 - t) * 2048 + j * 32 + ii];
  }
}

// ---------------- generic fp32 GEMM, 64x64 tile, BK=32 ----------------
// MODE 0: out[(c)*64 + m]  (transposed, for VT)
// MODE 1: fused unpack epilogue to d_out (rows r' = i*16+t -> out[i*N + c*16+t])
template <int MODE>
__global__ __launch_bounds__(256) void k_gemm(const float* __restrict__ Am,
                                              const float* __restrict__ Bm,
                                              float* __restrict__ outp,
                                              int Kdim) {
  __shared__ __align__(16) float smem[4608];
  float* As = smem;          // [32][68] transposed: As[k][m]
  float* Bs = smem + 2176;   // [32][68]: Bs[k][n]
  const int tid = threadIdx.x;
  const int ty = tid >> 4, tx = tid & 15;
  const int c0 = blockIdx.x * 64;
  const int m0 = blockIdx.y * 64;
  const int am = tid >> 2, ak0 = (tid & 3) << 3;
  const int bk = tid >> 3, bn0 = (tid & 7) << 3;
  float acc[4][4] = {};
  for (int kk = 0; kk < Kdim; kk += 32) {
    const float4 a0 = *reinterpret_cast<const float4*>(Am + (size_t)(m0 + am) * Kdim + kk + ak0);
    const float4 a1 = *reinterpret_cast<const float4*>(Am + (size_t)(m0 + am) * Kdim + kk + ak0 + 4);
    const float4 b0 = *reinterpret_cast<const float4*>(Bm + (size_t)(kk + bk) * CCH + c0 + bn0);
    const float4 b1 = *reinterpret_cast<const float4*>(Bm + (size_t)(kk + bk) * CCH + c0 + bn0 + 4);
    __syncthreads();
    As[(ak0 + 0) * 68 + am] = a0.x; As[(ak0 + 1) * 68 + am] = a0.y;
    As[(ak0 + 2) * 68 + am] = a0.z; As[(ak0 + 3) * 68 + am] = a0.w;
    As[(ak0 + 4) * 68 + am] = a1.x; As[(ak0 + 5) * 68 + am] = a1.y;
    As[(ak0 + 6) * 68 + am] = a1.z; As[(ak0 + 7) * 68 + am] = a1.w;
    *reinterpret_cast<float4*>(&Bs[bk * 68 + bn0]) = b0;
    *reinterpret_cast<float4*>(&Bs[bk * 68 + bn0 + 4]) = b1;
    __syncthreads();
#pragma unroll
    for (int k = 0; k < 32; ++k) {
      const float4 av = *reinterpret_cast<const float4*>(&As[k * 68 + (ty << 2)]);
      const float4 bv = *reinterpret_cast<const float4*>(&Bs[k * 68 + (tx << 2)]);
      const float aa[4] = {av.x, av.y, av.z, av.w};
      const float bb[4] = {bv.x, bv.y, bv.z, bv.w};
#pragma unroll
      for (int a = 0; a < 4; ++a)
#pragma unroll
        for (int b = 0; b < 4; ++b) acc[a][b] = fmaf(aa[a], bb[b], acc[a][b]);
    }
  }
  if (MODE == 0) {
#pragma unroll
    for (int b = 0; b < 4; ++b) {
      const float4 vv = make_float4(acc[0][b], acc[1][b], acc[2][b], acc[3][b]);
      *reinterpret_cast<float4*>(outp + (size_t)(c0 + (tx << 2) + b) * 64 + m0 + (ty << 2)) = vv;
    }
  } else {
    __syncthreads();
#pragma unroll
    for (int a = 0; a < 4; ++a)
#pragma unroll
      for (int b = 0; b < 4; ++b)
        smem[(ty * 4 + a) * 65 + tx * 4 + b] = acc[a][b];
    __syncthreads();
    const int il = tid >> 6, cl = tid & 63;
    const int i = (m0 >> 4) + il;                 // global observation row
    float* dst = outp + (size_t)i * NSTEP + (size_t)c0 * 16 + cl * 16;
    float vv[16];
#pragma unroll
    for (int t16 = 0; t16 < 16; ++t16) vv[t16] = smem[(il * 16 + t16) * 65 + cl];
#pragma unroll
    for (int w = 0; w < 4; ++w)
      *reinterpret_cast<float4*>(dst + w * 4) =
          make_float4(vv[w * 4], vv[w * 4 + 1], vv[w * 4 + 2], vv[w * 4 + 3]);
  }
}

// ---------------- scan matvec: row-in-registers + readlane broadcast ----------------
__device__ __forceinline__ float lane_bcast(float v, int l) {
  return __uint_as_float(__builtin_amdgcn_readlane(__float_as_uint(v), l));
}

__device__ __forceinline__ float matvec_step(const float* __restrict__ Prow, float x,
                                             float v) {
  float accA = v, accB = 0.f;
#pragma unroll
  for (int j = 0; j < 32; ++j) {
    accA = fmaf(Prow[j], lane_bcast(x, j), accA);
    accB = fmaf(Prow[j + 32], lane_bcast(x, j + 32), accB);
  }
  return accA + accB;
}

__global__ __launch_bounds__(64) void k_scanA(const float* __restrict__ MP,
                                              const float* __restrict__ VT,
                                              float* __restrict__ W) {
  const int lane = threadIdx.x;
  const int b = blockIdx.x;
  const float* P = MP + 4 * 4096;   // M^16
  float Prow[64];
#pragma unroll
  for (int j = 0; j < 64; ++j) Prow[j] = P[lane * 64 + j];
  const float* vbase = VT + (size_t)b * SB * 64;
  float x = 0.f;
  float v0 = vbase[lane];
  float v1 = vbase[64 + lane];
  for (int s = 0; s < SB; ++s) {
    x = matvec_step(Prow, x, v0);
    v0 = v1;
    v1 = (s + 2 < SB) ? vbase[(size_t)(s + 2) * 64 + lane] : 0.f;
  }
  W[b * 64 + lane] = x;
}

__global__ __launch_bounds__(64) void k_scanB(const float* __restrict__ MP,
                                              const float* __restrict__ W,
                                              float* __restrict__ XB) {
  const int lane = threadIdx.x;
  const float* Q = MP + 5 * 4096;   // M^2048
  float Qrow[64];
#pragma unroll
  for (int j = 0; j < 64; ++j) Qrow[j] = Q[lane * 64 + j];
  float x = 0.f;
  float v0 = W[lane];
  float v1 = W[64 + lane];
  for (int b = 0; b < NBLK; ++b) {
    XB[b * 64 + lane] = x;          // state at start of scan-block b
    x = matvec_step(Qrow, x, v0);
    v0 = v1;
    v1 = (b + 2 < NBLK) ? W[(b + 2) * 64 + lane] : 0.f;
  }
}

__global__ __launch_bounds__(64) void k_scanC(const float* __restrict__ MP,
                                              const float* __restrict__ VT,
                                              const float* __restrict__ XB,
                                              float* __restrict__ Z) {
  __shared__ float xt[64 * 129];
  const int lane = threadIdx.x;
  const int b = blockIdx.x;
  const float* P = MP + 4 * 4096;
  float Prow[64];
#pragma unroll
  for (int j = 0; j < 64; ++j) Prow[j] = P[lane * 64 + j];
  const float* vbase = VT + (size_t)b * SB * 64;
  float x = XB[b * 64 + lane];
  float v0 = vbase[lane];
  float v1 = vbase[64 + lane];
  for (int s = 0; s < SB; ++s) {
    xt[lane * 129 + s] = x;         // x_c BEFORE consuming v_c
    x = matvec_step(Prow, x, v0);
    v0 = v1;
    v1 = (s + 2 < SB) ? vbase[(size_t)(s + 2) * 64 + lane] : 0.f;
  }
  __syncthreads();
  for (int e = lane; e < 64 * SB; e += 64) {   // coalesced write to Z rows 0..63
    const int i = e >> 7, j = e & 127;
    Z[(size_t)i * CCH + b * SB + j] = xt[i * 129 + j];
  }
}

extern "C" void kernel_launch(void* const* d_in, const int* in_sizes, int n_in,
                              void* d_out, int out_size, void* d_ws, size_t ws_size,
                              hipStream_t stream) {
  const float* y = (const float*)d_in[0];
  const float* A = (const float*)d_in[1];
  const float* H = (const float*)d_in[2];
  const float* L = (const float*)d_in[3];
  float* ws = (float*)d_ws;
  float* Z  = ws + OFF_Z;
  float* VT = ws + OFF_VT;
  float* MP = ws + OFF_MP;
  float* BO = ws + OFF_BO;
  float* GC = ws + OFF_GC;
  float* W  = ws + OFF_W;
  float* XB = ws + OFF_XB;
  float* out = (float*)d_out;

  k_pack<<<dim3(32 * (NSTEP / 4) / 256), dim3(256), 0, stream>>>(y, Z);
  k_p1<<<dim3(1), dim3(1024), 0, stream>>>(A, H, L, MP);
  k_p2<<<dim3(1), dim3(1024), 0, stream>>>(H, L, MP, ws);
  // V GEMM: VT[c][j] = (Gcat x Ypack)[j][c]
  k_gemm<0><<<dim3(CCH / 64, 1), dim3(256), 0, stream>>>(GC, Z + (size_t)64 * CCH, VT, 512);
  k_scanA<<<dim3(NBLK), dim3(64), 0, stream>>>(MP, VT, W);
  k_scanB<<<dim3(1), dim3(64), 0, stream>>>(MP, W, XB);
  k_scanC<<<dim3(NBLK), dim3(64), 0, stream>>>(MP, VT, XB, Z);
  // Output GEMM with fused unpack epilogue
  k_gemm<1><<<dim3(CCH / 64, MOUT / 64), dim3(256), 0, stream>>>(BO, Z, out, KDIM);
}

// Round 3
// 540.649 us; speedup vs baseline: 2.0827x; 2.0827x over previous
//
#include <hip/hip_runtime.h>
#include <hip/hip_bf16.h>

// Kalman recurrence, exact chunked parallelization (all fp32, round 2 resubmit).
//   x[k+1] = M x[k] + L y[:,k],  M = A - L H,  yhat[:,k] = H x[k], x[0]=0
// Chunk T=16:  yhat[cT+t] = F_t x_c + sum_{s<t} K_{t-1-s} y[cT+s]
//   F_t = H M^t (32x64), K_d = H M^d L (32x32), v_c = sum_t M^{T-1-t} L y[cT+t]
//   x_{c+1} = P x_c + v_c, P = M^16.  3-level scan over C=16384 chunks.
// Round-2 change: k_p2 rebuilt around LDS (volatile-global RAW chain was 737us).

#define NSTEP 262144
#define T 16
#define CCH (NSTEP / T)          // 16384 chunks
#define KDIM (64 + 32 * T)       // 576
#define MOUT (32 * T)            // 512
#define NBLK 128                 // scan blocks
#define SB (CCH / NBLK)          // 128 chunks per scan block

// ---- workspace layout (floats) ----
#define OFF_Z  0                         // Z: [576][CCH]  rows 0..63 = x_c, 64.. = packed y
#define SZ_Z   (KDIM * CCH)
#define OFF_VT (OFF_Z + SZ_Z)            // VT: [CCH][64]  chunk summaries v_c (transposed)
#define SZ_VT  (CCH * 64)
#define OFF_MP (OFF_VT + SZ_VT)          // M powers: slots {M,M2,M4,M8,M16=P,M2048=Q} x4096
#define SZ_MP  (6 * 4096)
#define OFF_BO (OFF_MP + SZ_MP)          // BigOut: [512][576], rows permuted r' = i*16 + t
#define SZ_BO  (MOUT * KDIM)
#define OFF_GC (OFF_BO + SZ_BO)          // Gcat: [64][512]
#define SZ_GC  (64 * 512)
#define OFF_W  (OFF_GC + SZ_GC)          // per-scan-block summaries w_b: [128][64]
#define SZ_W   (NBLK * 64)
#define OFF_XB (OFF_W + SZ_W)            // block start states X_b: [128][64]

// ---------------- pack: Z[64 + t*32 + i][c] = y[i][c*16+t] ----------------
__global__ __launch_bounds__(256) void k_pack(const float* __restrict__ y,
                                              float* __restrict__ Z) {
  int g = blockIdx.x * 256 + threadIdx.x;      // over 32 * 65536 float4s
  int i = g >> 16;
  int k0 = (g & 65535) << 2;
  int c = k0 >> 4;
  int t0 = k0 & 15;
  const float4 v = *reinterpret_cast<const float4*>(y + (size_t)i * NSTEP + k0);
  size_t base = (size_t)(64 + t0 * 32 + i) * CCH + c;
  Z[base] = v.x;
  Z[base + (size_t)32 * CCH] = v.y;
  Z[base + (size_t)64 * CCH] = v.z;
  Z[base + (size_t)96 * CCH] = v.w;
}

// ------------- P1: M = A - L H, then squaring chain in LDS -------------
__global__ __launch_bounds__(1024) void k_p1(const float* __restrict__ A,
                                             const float* __restrict__ H,
                                             const float* __restrict__ L,
                                             float* __restrict__ MP) {
  __shared__ float sm[2][64 * 68];
  const int tid = threadIdx.x;
  const int i = tid >> 4;
  const int j0 = (tid & 15) << 2;
  float a0 = A[i * 64 + j0 + 0], a1 = A[i * 64 + j0 + 1];
  float a2 = A[i * 64 + j0 + 2], a3 = A[i * 64 + j0 + 3];
  for (int q = 0; q < 32; ++q) {
    const float l = L[i * 32 + q];
    a0 -= l * H[q * 64 + j0 + 0];
    a1 -= l * H[q * 64 + j0 + 1];
    a2 -= l * H[q * 64 + j0 + 2];
    a3 -= l * H[q * 64 + j0 + 3];
  }
  sm[0][i * 68 + j0 + 0] = a0; sm[0][i * 68 + j0 + 1] = a1;
  sm[0][i * 68 + j0 + 2] = a2; sm[0][i * 68 + j0 + 3] = a3;
  MP[i * 64 + j0 + 0] = a0; MP[i * 64 + j0 + 1] = a1;
  MP[i * 64 + j0 + 2] = a2; MP[i * 64 + j0 + 3] = a3;
  __syncthreads();
  int cur = 0;
  for (int s = 1; s <= 11; ++s) {   // powers 2,4,8,16,...,2048
    float c0 = 0.f, c1 = 0.f, c2 = 0.f, c3 = 0.f;
    for (int k = 0; k < 64; ++k) {
      const float r = sm[cur][i * 68 + k];
      const float* col = &sm[cur][k * 68 + j0];
      c0 += r * col[0]; c1 += r * col[1]; c2 += r * col[2]; c3 += r * col[3];
    }
    sm[cur ^ 1][i * 68 + j0 + 0] = c0; sm[cur ^ 1][i * 68 + j0 + 1] = c1;
    sm[cur ^ 1][i * 68 + j0 + 2] = c2; sm[cur ^ 1][i * 68 + j0 + 3] = c3;
    const int slot = (s <= 4) ? s : (s == 11 ? 5 : -1);
    if (slot >= 0) {
      MP[slot * 4096 + i * 64 + j0 + 0] = c0;
      MP[slot * 4096 + i * 64 + j0 + 1] = c1;
      MP[slot * 4096 + i * 64 + j0 + 2] = c2;
      MP[slot * 4096 + i * 64 + j0 + 3] = c3;
    }
    cur ^= 1;
    __syncthreads();
  }
}

// ------ P2 (LDS version): block 0 = F chain + BigOut + K scatter;
//        block 1 = G chain + Gcat.  S = 16 x 2048 floats = 128 KiB LDS. ------
__global__ __launch_bounds__(1024) void k_p2(const float* __restrict__ H,
                                             const float* __restrict__ L,
                                             const float* __restrict__ MP,
                                             float* __restrict__ ws) {
  __shared__ float S[16 * 2048];   // F_t or G_t, t = 0..15
  float* BO = ws + OFF_BO;
  float* GC = ws + OFF_GC;
  const int tid = threadIdx.x;

  if (blockIdx.x == 0) {
    // ---- F chain: F_0 = H; F_{t+nf} = F_t * M^{nf} ----
    for (int e = tid; e < 2048; e += 1024) S[e] = H[e];
    __syncthreads();
    for (int r = 0; r < 4; ++r) {
      const int nf = 1 << r;
      const float* __restrict__ Mp = MP + r * 4096;   // M^{2^r}
      // read S[0 .. nf*2048), write S[nf*2048 .. 2nf*2048) — disjoint
      for (int e = tid; e < nf * 2048; e += 1024) {
        const int t = e >> 11, i = (e >> 6) & 31, j = e & 63;
        const float* Frow = &S[t * 2048 + i * 64];     // broadcast across lanes
        float acc = 0.f;
#pragma unroll 8
        for (int q = 0; q < 64; ++q) acc = fmaf(Frow[q], Mp[q * 64 + j], acc);
        S[nf * 2048 + e] = acc;
      }
      __syncthreads();
    }
    // ---- BigOut F-part and zero-part (K region s<t left for scatter) ----
    for (int e = tid; e < MOUT * KDIM; e += 1024) {
      const int rr = e / KDIM;
      const int f = e - rr * KDIM;
      const int i = rr >> 4;
      const int t = rr & 15;
      if (f < 64) {
        BO[e] = S[t * 2048 + i * 64 + f];
      } else {
        const int s = (f - 64) >> 5;
        if (s >= t) BO[e] = 0.f;   // else: K scatter writes it (disjoint)
      }
    }
    // ---- K_d = F_d * L, scattered to BigOut[(i*16+t)*576 + 64+(t-1-d)*32+q] ----
    for (int e = tid; e < 15 * 1024; e += 1024) {
      const int d = e >> 10, i = (e >> 5) & 31, q = e & 31;
      const float* Frow = &S[d * 2048 + i * 64];
      float kv = 0.f;
#pragma unroll 8
      for (int j = 0; j < 64; ++j) kv = fmaf(Frow[j], L[j * 32 + q], kv);
      for (int t = d + 1; t < 16; ++t) {
        BO[(size_t)(i * 16 + t) * KDIM + 64 + (t - 1 - d) * 32 + q] = kv;
      }
    }
  } else {
    // ---- G chain: G_0 = L; G_{t+nf} = M^{nf} * G_t ----
    for (int e = tid; e < 2048; e += 1024) S[e] = L[e];
    __syncthreads();
    for (int r = 0; r < 4; ++r) {
      const int nf = 1 << r;
      const float* __restrict__ Mp = MP + r * 4096;
      for (int e = tid; e < nf * 2048; e += 1024) {
        const int t = e >> 11, i = (e >> 5) & 63, q = e & 31;
        const float* Mrow = Mp + i * 64;
        float acc = 0.f;
#pragma unroll 8
        for (int p = 0; p < 64; ++p) acc = fmaf(Mrow[p], S[t * 2048 + p * 32 + q], acc);
        S[nf * 2048 + e] = acc;
      }
      __syncthreads();
    }
    // ---- Gcat[j][t*32+ii] = G_{15-t}[j][ii] ----
    for (int e = tid; e < 64 * 512; e += 1024) {
      const int j = e >> 9, f = e & 511, t = f >> 5, ii = f & 31;
      GC[e] = S[(15 - t) * 2048 + j * 32 + ii];
    }
  }
}

// ---------------- generic fp32 GEMM, 64x64 tile, BK=32 ----------------
// MODE 0: out[(c)*64 + m]  (transposed, for VT)
// MODE 1: fused unpack epilogue to d_out (rows r' = i*16+t -> out[i*N + c*16+t])
template <int MODE>
__global__ __launch_bounds__(256) void k_gemm(const float* __restrict__ Am,
                                              const float* __restrict__ Bm,
                                              float* __restrict__ outp,
                                              int Kdim) {
  __shared__ __align__(16) float smem[4608];
  float* As = smem;          // [32][68] transposed: As[k][m]
  float* Bs = smem + 2176;   // [32][68]: Bs[k][n]
  const int tid = threadIdx.x;
  const int ty = tid >> 4, tx = tid & 15;
  const int c0 = blockIdx.x * 64;
  const int m0 = blockIdx.y * 64;
  const int am = tid >> 2, ak0 = (tid & 3) << 3;
  const int bk = tid >> 3, bn0 = (tid & 7) << 3;
  float acc[4][4] = {};
  for (int kk = 0; kk < Kdim; kk += 32) {
    const float4 a0 = *reinterpret_cast<const float4*>(Am + (size_t)(m0 + am) * Kdim + kk + ak0);
    const float4 a1 = *reinterpret_cast<const float4*>(Am + (size_t)(m0 + am) * Kdim + kk + ak0 + 4);
    const float4 b0 = *reinterpret_cast<const float4*>(Bm + (size_t)(kk + bk) * CCH + c0 + bn0);
    const float4 b1 = *reinterpret_cast<const float4*>(Bm + (size_t)(kk + bk) * CCH + c0 + bn0 + 4);
    __syncthreads();
    As[(ak0 + 0) * 68 + am] = a0.x; As[(ak0 + 1) * 68 + am] = a0.y;
    As[(ak0 + 2) * 68 + am] = a0.z; As[(ak0 + 3) * 68 + am] = a0.w;
    As[(ak0 + 4) * 68 + am] = a1.x; As[(ak0 + 5) * 68 + am] = a1.y;
    As[(ak0 + 6) * 68 + am] = a1.z; As[(ak0 + 7) * 68 + am] = a1.w;
    *reinterpret_cast<float4*>(&Bs[bk * 68 + bn0]) = b0;
    *reinterpret_cast<float4*>(&Bs[bk * 68 + bn0 + 4]) = b1;
    __syncthreads();
#pragma unroll
    for (int k = 0; k < 32; ++k) {
      const float4 av = *reinterpret_cast<const float4*>(&As[k * 68 + (ty << 2)]);
      const float4 bv = *reinterpret_cast<const float4*>(&Bs[k * 68 + (tx << 2)]);
      const float aa[4] = {av.x, av.y, av.z, av.w};
      const float bb[4] = {bv.x, bv.y, bv.z, bv.w};
#pragma unroll
      for (int a = 0; a < 4; ++a)
#pragma unroll
        for (int b = 0; b < 4; ++b) acc[a][b] = fmaf(aa[a], bb[b], acc[a][b]);
    }
  }
  if (MODE == 0) {
#pragma unroll
    for (int b = 0; b < 4; ++b) {
      const float4 vv = make_float4(acc[0][b], acc[1][b], acc[2][b], acc[3][b]);
      *reinterpret_cast<float4*>(outp + (size_t)(c0 + (tx << 2) + b) * 64 + m0 + (ty << 2)) = vv;
    }
  } else {
    __syncthreads();
#pragma unroll
    for (int a = 0; a < 4; ++a)
#pragma unroll
      for (int b = 0; b < 4; ++b)
        smem[(ty * 4 + a) * 65 + tx * 4 + b] = acc[a][b];
    __syncthreads();
    const int il = tid >> 6, cl = tid & 63;
    const int i = (m0 >> 4) + il;                 // global observation row
    float* dst = outp + (size_t)i * NSTEP + (size_t)c0 * 16 + cl * 16;
    float vv[16];
#pragma unroll
    for (int t16 = 0; t16 < 16; ++t16) vv[t16] = smem[(il * 16 + t16) * 65 + cl];
#pragma unroll
    for (int w = 0; w < 4; ++w)
      *reinterpret_cast<float4*>(dst + w * 4) =
          make_float4(vv[w * 4], vv[w * 4 + 1], vv[w * 4 + 2], vv[w * 4 + 3]);
  }
}

// ---------------- scan matvec: row-in-registers + readlane broadcast ----------------
__device__ __forceinline__ float lane_bcast(float v, int l) {
  return __uint_as_float(__builtin_amdgcn_readlane(__float_as_uint(v), l));
}

__device__ __forceinline__ float matvec_step(const float* __restrict__ Prow, float x,
                                             float v) {
  float accA = v, accB = 0.f;
#pragma unroll
  for (int j = 0; j < 32; ++j) {
    accA = fmaf(Prow[j], lane_bcast(x, j), accA);
    accB = fmaf(Prow[j + 32], lane_bcast(x, j + 32), accB);
  }
  return accA + accB;
}

__global__ __launch_bounds__(64) void k_scanA(const float* __restrict__ MP,
                                              const float* __restrict__ VT,
                                              float* __restrict__ W) {
  const int lane = threadIdx.x;
  const int b = blockIdx.x;
  const float* P = MP + 4 * 4096;   // M^16
  float Prow[64];
#pragma unroll
  for (int j = 0; j < 64; ++j) Prow[j] = P[lane * 64 + j];
  const float* vbase = VT + (size_t)b * SB * 64;
  float x = 0.f;
  float v0 = vbase[lane];
  float v1 = vbase[64 + lane];
  for (int s = 0; s < SB; ++s) {
    x = matvec_step(Prow, x, v0);
    v0 = v1;
    v1 = (s + 2 < SB) ? vbase[(size_t)(s + 2) * 64 + lane] : 0.f;
  }
  W[b * 64 + lane] = x;
}

__global__ __launch_bounds__(64) void k_scanB(const float* __restrict__ MP,
                                              const float* __restrict__ W,
                                              float* __restrict__ XB) {
  const int lane = threadIdx.x;
  const float* Q = MP + 5 * 4096;   // M^2048
  float Qrow[64];
#pragma unroll
  for (int j = 0; j < 64; ++j) Qrow[j] = Q[lane * 64 + j];
  float x = 0.f;
  float v0 = W[lane];
  float v1 = W[64 + lane];
  for (int b = 0; b < NBLK; ++b) {
    XB[b * 64 + lane] = x;          // state at start of scan-block b
    x = matvec_step(Qrow, x, v0);
    v0 = v1;
    v1 = (b + 2 < NBLK) ? W[(b + 2) * 64 + lane] : 0.f;
  }
}

__global__ __launch_bounds__(64) void k_scanC(const float* __restrict__ MP,
                                              const float* __restrict__ VT,
                                              const float* __restrict__ XB,
                                              float* __restrict__ Z) {
  __shared__ float xt[64 * 129];
  const int lane = threadIdx.x;
  const int b = blockIdx.x;
  const float* P = MP + 4 * 4096;
  float Prow[64];
#pragma unroll
  for (int j = 0; j < 64; ++j) Prow[j] = P[lane * 64 + j];
  const float* vbase = VT + (size_t)b * SB * 64;
  float x = XB[b * 64 + lane];
  float v0 = vbase[lane];
  float v1 = vbase[64 + lane];
  for (int s = 0; s < SB; ++s) {
    xt[lane * 129 + s] = x;         // x_c BEFORE consuming v_c
    x = matvec_step(Prow, x, v0);
    v0 = v1;
    v1 = (s + 2 < SB) ? vbase[(size_t)(s + 2) * 64 + lane] : 0.f;
  }
  __syncthreads();
  for (int e = lane; e < 64 * SB; e += 64) {   // coalesced write to Z rows 0..63
    const int i = e >> 7, j = e & 127;
    Z[(size_t)i * CCH + b * SB + j] = xt[i * 129 + j];
  }
}

extern "C" void kernel_launch(void* const* d_in, const int* in_sizes, int n_in,
                              void* d_out, int out_size, void* d_ws, size_t ws_size,
                              hipStream_t stream) {
  const float* y = (const float*)d_in[0];
  const float* A = (const float*)d_in[1];
  const float* H = (const float*)d_in[2];
  const float* L = (const float*)d_in[3];
  float* ws = (float*)d_ws;
  float* Z  = ws + OFF_Z;
  float* VT = ws + OFF_VT;
  float* MP = ws + OFF_MP;
  float* BO = ws + OFF_BO;
  float* GC = ws + OFF_GC;
  float* W  = ws + OFF_W;
  float* XB = ws + OFF_XB;
  float* out = (float*)d_out;

  k_pack<<<dim3(32 * (NSTEP / 4) / 256), dim3(256), 0, stream>>>(y, Z);
  k_p1<<<dim3(1), dim3(1024), 0, stream>>>(A, H, L, MP);
  k_p2<<<dim3(2), dim3(1024), 0, stream>>>(H, L, MP, ws);
  // V GEMM: VT[c][j] = (Gcat x Ypack)[j][c]
  k_gemm<0><<<dim3(CCH / 64, 1), dim3(256), 0, stream>>>(GC, Z + (size_t)64 * CCH, VT, 512);
  k_scanA<<<dim3(NBLK), dim3(64), 0, stream>>>(MP, VT, W);
  k_scanB<<<dim3(1), dim3(64), 0, stream>>>(MP, W, XB);
  k_scanC<<<dim3(NBLK), dim3(64), 0, stream>>>(MP, VT, XB, Z);
  // Output GEMM with fused unpack epilogue
  k_gemm<1><<<dim3(CCH / 64, MOUT / 64), dim3(256), 0, stream>>>(BO, Z, out, KDIM);
}